// Round 5
// baseline (543.756 us; speedup 1.0000x reference)
//
#include <hip/hip_runtime.h>
#include <cstdint>
#include <cstddef>

#define NB 16
#define NC 84
#define NA 33600
#define NCLS 80
#define TOPK 1024
#define NBIN 8192        // coarse bins: mono_u32 >> 19
#define CANDCAP 8192
#define SELCAP 2048
#define SCORE_THR 0.005f
#define IOU_THR 0.5f
#define MEGA_NBLK 128    // <= half the CUs: co-residency guaranteed

// ---- 64-bit sort key: (monotonic fp32) << 32 | ~index ----------------------
// Larger key == (higher score, then lower index) == jax.lax.top_k order.
__device__ __forceinline__ unsigned mono_u32(float f) {
    unsigned u = __float_as_uint(f);
    return (u & 0x80000000u) ? ~u : (u | 0x80000000u);
}
__device__ __forceinline__ float key_val(uint64_t k) {
    unsigned u = (unsigned)(k >> 32);
    u = (u & 0x80000000u) ? (u & 0x7FFFFFFFu) : ~u;
    return __uint_as_float(u);
}
__device__ __forceinline__ int key_idx(uint64_t k) {
    return (int)(~(uint32_t)(k & 0xFFFFFFFFu));
}

// ---- Kernel 1: per-anchor max/argmax (float4) + zero-init barrier state ----
__global__ __launch_bounds__(256) void score_kernel(const float* __restrict__ x,
                                                    float* __restrict__ sval,
                                                    int* __restrict__ cid,
                                                    unsigned* __restrict__ bar,
                                                    unsigned* __restrict__ cnt) {
    if (blockIdx.x == 0) {           // init for mega_kernel (visible at kernel boundary)
        if (threadIdx.x < 8) bar[threadIdx.x] = 0;
        cnt[threadIdx.x] = 0;        // NB*16 = 256 entries
    }
    int gid = blockIdx.x * 256 + threadIdx.x;     // NB*NA/4 threads
    if (gid >= NB * (NA / 4)) return;
    int b = gid / (NA / 4);
    int q = gid - b * (NA / 4);
    const float4* p = (const float4*)(x + (size_t)b * NC * NA + (size_t)4 * NA) + q;
    float4 best = p[0];
    int4 bc = {0, 0, 0, 0};
#pragma unroll 8
    for (int c = 1; c < NCLS; ++c) {
        float4 v = p[(size_t)c * (NA / 4)];
        if (v.x > best.x) { best.x = v.x; bc.x = c; }
        if (v.y > best.y) { best.y = v.y; bc.y = c; }
        if (v.z > best.z) { best.z = v.z; bc.z = c; }
        if (v.w > best.w) { best.w = v.w; bc.w = c; }
    }
    float4 s;
    s.x = (best.x > SCORE_THR) ? best.x : -INFINITY;
    s.y = (best.y > SCORE_THR) ? best.y : -INFINITY;
    s.z = (best.z > SCORE_THR) ? best.z : -INFINITY;
    s.w = (best.w > SCORE_THR) ? best.w : -INFINITY;
    ((float4*)sval)[gid] = s;
    ((int4*)cid)[gid] = bc;
}

// ---- device-scope single-use grid barrier (counters pre-zeroed) ------------
__device__ __forceinline__ void grid_barrier(unsigned* bar, int id) {
    __syncthreads();
    __threadfence();
    if (threadIdx.x == 0) {
        __hip_atomic_fetch_add(&bar[id], 1u, __ATOMIC_ACQ_REL, __HIP_MEMORY_SCOPE_AGENT);
        while (__hip_atomic_load(&bar[id], __ATOMIC_ACQUIRE, __HIP_MEMORY_SCOPE_AGENT)
               < (unsigned)MEGA_NBLK)
            __builtin_amdgcn_s_sleep(8);
    }
    __syncthreads();
    __threadfence();
}

__device__ __forceinline__ void bitonic_desc(uint64_t* A, int n, int tid) {
    for (int k = 2; k <= n; k <<= 1) {
        for (int j = k >> 1; j > 0; j >>= 1) {
            for (int i = tid; i < n; i += 256) {
                int ixj = i ^ j;
                if (ixj > i) {
                    uint64_t a = A[i], b2 = A[ixj];
                    bool up = ((i & k) == 0);
                    if (up ? (a < b2) : (a > b2)) { A[i] = b2; A[ixj] = a; }
                }
            }
            __syncthreads();
        }
    }
}

#define LDSPAD(j) ((j) + ((j) >> 6))

// ---- Kernel 2: everything else, phased with grid barriers ------------------
__global__ __launch_bounds__(256) void mega_kernel(const float* __restrict__ x,
                                                   const float* __restrict__ sval,
                                                   const int* __restrict__ cid,
                                                   unsigned* __restrict__ bar,
                                                   unsigned* __restrict__ cnt,
                                                   unsigned* __restrict__ cutbin,
                                                   uint64_t* __restrict__ cand,
                                                   float* __restrict__ tval,
                                                   float* __restrict__ bx1, float* __restrict__ by1,
                                                   float* __restrict__ bx2, float* __restrict__ by2,
                                                   float* __restrict__ barr, int* __restrict__ tcid,
                                                   uint64_t* __restrict__ M,
                                                   int* __restrict__ rowflag,
                                                   float* __restrict__ out) {
    __shared__ __align__(16) char smem[81920];   // phase-union (80 KB)
    __shared__ unsigned csum[256], sh[256];
    __shared__ int anyf[256];
    __shared__ unsigned snA, snSel, ssubcut, lc, lbase;
    const int t = threadIdx.x;
    const int g = blockIdx.x;

    // ---- P0: per-batch LDS histogram + scan -> cutbin (blocks 0..15) ----
    if (g < NB) {
        unsigned* h = (unsigned*)smem;
        for (int i = t; i < NBIN; i += 256) h[i] = 0;
        __syncthreads();
        const float4* sv4 = (const float4*)(sval + (size_t)g * NA);
        for (int i = t; i < NA / 4; i += 256) {
            float4 v = sv4[i];
            atomicAdd(&h[mono_u32(v.x) >> 19], 1u);
            atomicAdd(&h[mono_u32(v.y) >> 19], 1u);
            atomicAdd(&h[mono_u32(v.z) >> 19], 1u);
            atomicAdd(&h[mono_u32(v.w) >> 19], 1u);
        }
        __syncthreads();
        unsigned local = 0;
#pragma unroll 8
        for (int q = 0; q < 32; ++q) local += h[NBIN - 1 - (t * 32 + q)];
        csum[t] = local;
        __syncthreads();
        for (int off = 1; off < 256; off <<= 1) {
            unsigned v = (t >= off) ? csum[t - off] : 0u;
            __syncthreads();
            csum[t] += v;
            __syncthreads();
        }
        unsigned incl = csum[t], excl = incl - local;
        if (excl < TOPK && incl >= TOPK) {
            unsigned cum = excl;
            for (int q = 0; q < 32; ++q) {
                unsigned bin = NBIN - 1 - (t * 32 + q);
                unsigned c = h[bin];
                if (cum + c >= TOPK) { cutbin[g] = bin; break; }
                cum += c;
            }
        }
    }
    grid_barrier(bar, 0);

    // ---- P1: compact candidates (all blocks; 8 slices per batch) ----
    {
        int b = g >> 3, s8 = g & 7;
        int a0 = s8 * (NA / 8), a1 = a0 + (NA / 8);    // 4200 anchors
        uint64_t* cbuf = (uint64_t*)smem;              // cap 4224 >= 4200
        if (t == 0) lc = 0;
        __syncthreads();
        unsigned cb = cutbin[b];
        const float* sv = sval + (size_t)b * NA;
        for (int a = a0 + t; a < a1; a += 256) {
            unsigned u = mono_u32(sv[a]);
            if ((u >> 19) >= cb) {
                unsigned pos = atomicAdd(&lc, 1u);
                cbuf[pos] = ((uint64_t)u << 32) | (uint32_t)(~(uint32_t)a);
            }
        }
        __syncthreads();
        if (t == 0) lbase = lc ? atomicAdd(&cnt[b * 16], lc) : 0u;
        __syncthreads();
        for (unsigned i = t; i < lc; i += 256) {
            unsigned p = lbase + i;
            if (p < CANDCAP) cand[((size_t)b << 13) + p] = cbuf[i];
        }
    }
    grid_barrier(bar, 1);

    // ---- P2: exact top-1024 select+sort + box gather (blocks 0..15) ----
    if (g < NB) {
        const int b = g;
        uint64_t* lk   = (uint64_t*)smem;            // 64 KB
        uint64_t* lsel = (uint64_t*)(smem + 65536);  // 16 KB
        unsigned C = cnt[b * 16];
        if (C > CANDCAP) C = CANDCAP;
        unsigned cb = cutbin[b];
        for (int i = t; i < CANDCAP; i += 256)
            lk[i] = (i < (int)C) ? cand[((size_t)b << 13) + i] : 0ULL;
        for (int i = t; i < SELCAP; i += 256) lsel[i] = 0ULL;
        sh[t] = 0;
        if (t == 0) { snA = 0; snSel = 0; }
        __syncthreads();

        unsigned myA = 0;
        for (int i = t; i < (int)C; i += 256) {
            unsigned u = (unsigned)(lk[i] >> 32);
            if ((u >> 19) > cb) myA++;
            else atomicAdd(&sh[(u >> 11) & 255u], 1u);
        }
        atomicAdd(&snA, myA);
        __syncthreads();
        if (t == 0) {
            unsigned r = TOPK - snA, cum = 0, sc = 0;
            for (int s = 255; s >= 0; --s) {
                cum += sh[s];
                if (cum >= r) { sc = (unsigned)s; break; }
            }
            ssubcut = sc;
        }
        __syncthreads();
        unsigned subcut = ssubcut;

        int lane = t & 63;
        for (int i = t; i < CANDCAP; i += 256) {
            unsigned u = (unsigned)(lk[i] >> 32);
            unsigned bin = u >> 19;
            bool sel = (bin > cb) || (bin == cb && ((u >> 11) & 255u) >= subcut);
            uint64_t mask = __ballot(sel);
            if (mask) {
                int ldr = __ffsll((unsigned long long)mask) - 1;
                unsigned base2 = 0;
                if (lane == ldr) base2 = atomicAdd(&snSel, (unsigned)__popcll(mask));
                base2 = __shfl(base2, ldr, 64);
                if (sel) {
                    unsigned p = base2 + (unsigned)__popcll(mask & ((1ULL << lane) - 1ULL));
                    if (p < SELCAP) lsel[p] = lk[i];
                }
            }
        }
        __syncthreads();
        uint64_t* buf;
        if (snSel <= SELCAP) { bitonic_desc(lsel, SELCAP, t); buf = lsel; }
        else                 { bitonic_desc(lk, CANDCAP, t);  buf = lk;  }

        int base = b << 10;
        const float* xb = x + (size_t)b * NC * NA;
        for (int k = t; k < TOPK; k += 256) {
            uint64_t key = buf[k];
            int idx = key_idx(key);
            tval[base + k] = key_val(key);
            float x1 = xb[idx], y1 = xb[NA + idx], x2 = xb[2 * NA + idx], y2 = xb[3 * NA + idx];
            bx1[base + k] = x1; by1[base + k] = y1;
            bx2[base + k] = x2; by2[base + k] = y2;
            barr[base + k] = (x2 - x1) * (y2 - y1);
            tcid[base + k] = cid[b * NA + idx];
        }
    }
    grid_barrier(bar, 2);

    // ---- P3: suppression bit-matrix (all blocks; 128 rows each) ----
    {
        int b = g >> 3;
        int base = b << 10;
        float* sx1 = (float*)smem;
        float* sy1 = sx1 + (TOPK + 16);
        float* sx2 = sy1 + (TOPK + 16);
        float* sy2 = sx2 + (TOPK + 16);
        float* sar = sy2 + (TOPK + 16);
        for (int j = t; j < TOPK; j += 256) {
            int ji = LDSPAD(j);
            sx1[ji] = bx1[base + j]; sy1[ji] = by1[base + j];
            sx2[ji] = bx2[base + j]; sy2[ji] = by2[base + j];
            sar[ji] = barr[base + j];
        }
        __syncthreads();
        int w = t & 15;
        for (int pass = 0; pass < 8; ++pass) {
            int r = (g & 7) * 128 + pass * 16 + (t >> 4);
            int ri = LDSPAD(r);
            float ix1 = sx1[ri], iy1 = sy1[ri], ix2 = sx2[ri], iy2 = sy2[ri], ia = sar[ri];
            uint64_t m = 0;
#pragma unroll 8
            for (int jj = 0; jj < 64; ++jj) {
                int j = (w << 6) + jj;
                int ji = w * 65 + jj;
                float ltx = fmaxf(ix1, sx1[ji]);
                float lty = fmaxf(iy1, sy1[ji]);
                float rbx = fminf(ix2, sx2[ji]);
                float rby = fminf(iy2, sy2[ji]);
                float ww = fmaxf(rbx - ltx, 0.0f);
                float hh = fmaxf(rby - lty, 0.0f);
                float inter = ww * hh;
                float uni = ia + sar[ji] - inter;      // same op order as reference
                float iou = inter / fmaxf(uni, 1e-9f);
                if (j > r && iou > IOU_THR) m |= (1ULL << jj);
            }
            M[(((size_t)(base + r)) << 4) + w] = m;
            anyf[t] = (m != 0ULL);
            __syncthreads();
            if (w == 0) {
                int any = 0;
#pragma unroll
                for (int q = 0; q < 16; ++q) any |= anyf[(t & ~15) + q];
                bool valid = tval[base + r] > SCORE_THR;
                rowflag[base + r] = (any && valid) ? 1 : 0;
            }
            __syncthreads();
        }
    }
    grid_barrier(bar, 3);

    // ---- P4: serial greedy sweep + epilogue (blocks 0..15, wave 0 only) ----
    // Single wave: no __syncthreads inside (would hang the other waves).
    if (g < NB && t < 64) {
        int b = g, l = t;
        int base = b << 10;
        int w = l & 15, gg = l >> 4;
        int* list = (int*)smem;

        float tv[16];
#pragma unroll
        for (int s = 0; s < 16; ++s) tv[s] = tval[base + (s << 6) + l];

        uint64_t vword = 0;
#pragma unroll
        for (int s = 0; s < 16; ++s) {
            uint64_t bal = __ballot(tv[s] > SCORE_THR);
            if (l == s) vword = bal;
        }

        int cnt2 = 0;
#pragma unroll
        for (int s = 0; s < 16; ++s) {
            int flag = rowflag[base + (s << 6) + l];
            uint64_t m = __ballot(flag != 0);
            if (flag) {
                int pos = cnt2 + __popcll(m & ((1ULL << l) - 1ULL));
                list[pos] = (s << 6) + l;
            }
            cnt2 += __popcll(m);
        }

        uint64_t remv = 0;
        for (int chunk = 0; chunk < cnt2; chunk += 64) {
            int m = min(64, cnt2 - chunk);
            int idx_l = chunk + l;
            int myi = list[(idx_l < cnt2) ? idx_l : 0];
            uint64_t rows[16];
#pragma unroll
            for (int q = 0; q < 16; ++q) {
                int it = chunk + q * 4 + gg;
                int it2 = (it < cnt2) ? it : 0;
                uint64_t v = M[(((size_t)(base + list[it2])) << 4) + w];
                rows[q] = (it < cnt2) ? v : 0ULL;
            }
            for (int r = 0; r < m; ++r) {
                int i = __shfl(myi, r, 64);
                uint64_t row = __shfl(rows[r >> 2], ((r & 3) << 4) + w, 64);
                uint64_t rb = __shfl(remv, i >> 6, 64);
                bool kept = !((rb >> (i & 63)) & 1ULL);
                remv |= (kept && l < 16) ? row : 0ULL;
            }
        }

        uint64_t kf = vword & ~remv;
#pragma unroll
        for (int s = 0; s < 16; ++s) {
            uint64_t kw = __shfl(kf, s, 64);
            bool kp = (kw >> l) & 1ULL;
            int k = (s << 6) + l;
            float x1 = bx1[base + k], y1 = by1[base + k];
            float x2 = bx2[base + k], y2 = by2[base + k];
            float* po = out + ((size_t)(base + k)) * 6;
            po[0] = kp ? x1 : 0.0f;
            po[1] = kp ? y1 : 0.0f;
            po[2] = kp ? x2 : 0.0f;
            po[3] = kp ? y2 : 0.0f;
            po[4] = kp ? tv[s] : 0.0f;
            po[5] = kp ? (float)tcid[base + k] : 0.0f;
            out[(size_t)NB * TOPK * 6 + base + k] = kp ? 1.0f : 0.0f;
        }
    }
}

extern "C" void kernel_launch(void* const* d_in, const int* in_sizes, int n_in,
                              void* d_out, int out_size, void* d_ws, size_t ws_size,
                              hipStream_t stream) {
    const float* x = (const float*)d_in[0];
    float* out = (float*)d_out;
    char* ws = (char*)d_ws;

    size_t off = 0;
    auto alloc = [&](size_t bytes) { void* p = ws + off; off = (off + bytes + 255) & ~(size_t)255; return p; };
    float*    sval    = (float*)alloc((size_t)NB * NA * 4);
    int*      cid     = (int*)alloc((size_t)NB * NA * 4);
    unsigned* bar     = (unsigned*)alloc(8 * 4);
    unsigned* cnt     = (unsigned*)alloc((size_t)NB * 16 * 4);
    unsigned* cutbin  = (unsigned*)alloc(NB * 4);
    uint64_t* cand    = (uint64_t*)alloc((size_t)NB * CANDCAP * 8);
    float*    tval    = (float*)alloc((size_t)NB * TOPK * 4);
    float*    bx1     = (float*)alloc((size_t)NB * TOPK * 4);
    float*    by1     = (float*)alloc((size_t)NB * TOPK * 4);
    float*    bx2     = (float*)alloc((size_t)NB * TOPK * 4);
    float*    by2     = (float*)alloc((size_t)NB * TOPK * 4);
    float*    barr    = (float*)alloc((size_t)NB * TOPK * 4);
    int*      tcid    = (int*)alloc((size_t)NB * TOPK * 4);
    int*      rowflag = (int*)alloc((size_t)NB * TOPK * 4);
    uint64_t* M       = (uint64_t*)alloc((size_t)NB * TOPK * 16 * 8);

    score_kernel<<<NB * (NA / 4) / 256, 256, 0, stream>>>(x, sval, cid, bar, cnt);
    mega_kernel<<<MEGA_NBLK, 256, 0, stream>>>(x, sval, cid, bar, cnt, cutbin, cand,
                                               tval, bx1, by1, bx2, by2, barr, tcid,
                                               M, rowflag, out);
}

// Round 6
// 433.525 us; speedup vs baseline: 1.2543x; 1.2543x over previous
//
#include <hip/hip_runtime.h>
#include <cstdint>
#include <cstddef>

#define NB 16
#define NC 84
#define NA 33600
#define NCLS 80
#define TOPK 1024
#define NBIN 8192        // coarse bins: mono_u32 >> 19
#define CANDCAP 8192
#define SCORE_THR 0.005f
#define IOU_THR 0.5f

// ---- 64-bit sort key: (monotonic fp32) << 32 | ~index ----------------------
// Larger key == (higher score, then lower index) == jax.lax.top_k order.
__device__ __forceinline__ unsigned mono_u32(float f) {
    unsigned u = __float_as_uint(f);
    return (u & 0x80000000u) ? ~u : (u | 0x80000000u);
}
__device__ __forceinline__ float key_val(uint64_t k) {
    unsigned u = (unsigned)(k >> 32);
    u = (u & 0x80000000u) ? (u & 0x7FFFFFFFu) : ~u;
    return __uint_as_float(u);
}
__device__ __forceinline__ int key_idx(uint64_t k) {
    return (int)(~(uint32_t)(k & 0xFFFFFFFFu));
}

// ---- K1: max/argmax over 80 classes (float4) + LDS-private histogram -------
// grid (33, NB): block handles 1024 anchors (256 float4) of one batch.
__global__ __launch_bounds__(256) void score_hist_kernel(const float* __restrict__ x,
                                                         float* __restrict__ sval,
                                                         int* __restrict__ cid,
                                                         unsigned* __restrict__ hist) {
    __shared__ unsigned h[NBIN];
    const int t = threadIdx.x;
    const int b = blockIdx.y;
    for (int i = t; i < NBIN; i += 256) h[i] = 0;
    __syncthreads();
    int q = blockIdx.x * 256 + t;                 // float4 index within batch
    if (q < NA / 4) {
        const float4* p = (const float4*)(x + (size_t)b * NC * NA + (size_t)4 * NA) + q;
        float4 best = p[0];
        int4 bc = {0, 0, 0, 0};
#pragma unroll 8
        for (int c = 1; c < NCLS; ++c) {
            float4 v = p[(size_t)c * (NA / 4)];
            if (v.x > best.x) { best.x = v.x; bc.x = c; }
            if (v.y > best.y) { best.y = v.y; bc.y = c; }
            if (v.z > best.z) { best.z = v.z; bc.z = c; }
            if (v.w > best.w) { best.w = v.w; bc.w = c; }
        }
        float4 s;
        s.x = (best.x > SCORE_THR) ? best.x : -INFINITY;
        s.y = (best.y > SCORE_THR) ? best.y : -INFINITY;
        s.z = (best.z > SCORE_THR) ? best.z : -INFINITY;
        s.w = (best.w > SCORE_THR) ? best.w : -INFINITY;
        ((float4*)sval)[(size_t)b * (NA / 4) + q] = s;
        ((int4*)cid)[(size_t)b * (NA / 4) + q] = bc;
        atomicAdd(&h[mono_u32(s.x) >> 19], 1u);
        atomicAdd(&h[mono_u32(s.y) >> 19], 1u);
        atomicAdd(&h[mono_u32(s.z) >> 19], 1u);
        atomicAdd(&h[mono_u32(s.w) >> 19], 1u);
    }
    __syncthreads();
    unsigned* gh = hist + (size_t)b * NBIN;
    for (int i = t; i < NBIN; i += 256) {
        unsigned v = h[i];
        if (v) atomicAdd(&gh[i], v);
    }
}

// ---- K2: per-block cutbin recompute + compact slice ------------------------
// grid (16, NB): each block scans the (L2-hot) hist, then compacts 2100 anchors.
__global__ __launch_bounds__(256) void select_kernel(const float* __restrict__ sval,
                                                     const unsigned* __restrict__ hist,
                                                     uint64_t* __restrict__ cand,
                                                     unsigned* __restrict__ cnt) {
    __shared__ unsigned csum[256];
    __shared__ unsigned scut, lc, lbase;
    __shared__ uint64_t cbuf[2112];
    const int t = threadIdx.x;
    const int b = blockIdx.y;
    const int sl = blockIdx.x;

    const unsigned* gh = hist + (size_t)b * NBIN;
    unsigned cnts[32];
    unsigned local = 0;
#pragma unroll
    for (int q = 0; q < 32; ++q) {
        cnts[q] = gh[NBIN - 1 - (t * 32 + q)];
        local += cnts[q];
    }
    csum[t] = local;
    __syncthreads();
    for (int off = 1; off < 256; off <<= 1) {
        unsigned v = (t >= off) ? csum[t - off] : 0u;
        __syncthreads();
        csum[t] += v;
        __syncthreads();
    }
    unsigned incl = csum[t], excl = incl - local;
    if (excl < TOPK && incl >= TOPK) {
        unsigned cum = excl;
#pragma unroll
        for (int q = 0; q < 32; ++q) {
            if (cum + cnts[q] >= TOPK) { scut = (unsigned)(NBIN - 1 - (t * 32 + q)); break; }
            cum += cnts[q];
        }
    }
    if (t == 0) lc = 0;
    __syncthreads();
    unsigned cb = scut;

    int a0 = sl * (NA / 16);
    const float* sv = sval + (size_t)b * NA;
    for (int a = a0 + t; a < a0 + NA / 16; a += 256) {
        unsigned u = mono_u32(sv[a]);
        if ((u >> 19) >= cb) {
            unsigned pos = atomicAdd(&lc, 1u);
            cbuf[pos] = ((uint64_t)u << 32) | (uint32_t)(~(uint32_t)a);
        }
    }
    __syncthreads();
    if (t == 0) lbase = lc ? atomicAdd(&cnt[b * 64], lc) : 0u;
    __syncthreads();
    for (unsigned i = t; i < lc; i += 256) {
        unsigned p = lbase + i;
        if (p < CANDCAP) cand[((size_t)b << 13) + p] = cbuf[i];
    }
}

// ---- K3: exact top-1024 by rank-counting + fused box/cid gather ------------
// grid (4, NB). Keys unique -> ranks unique -> output bit-identical to top_k.
__global__ __launch_bounds__(256) void rank_gather_kernel(const float* __restrict__ x,
                                                          const int* __restrict__ cid,
                                                          const uint64_t* __restrict__ cand,
                                                          const unsigned* __restrict__ cnt,
                                                          float* __restrict__ tval,
                                                          float* __restrict__ bx1, float* __restrict__ by1,
                                                          float* __restrict__ bx2, float* __restrict__ by2,
                                                          float* __restrict__ barr, int* __restrict__ tcid) {
    __shared__ uint64_t lk[CANDCAP];   // 64 KB
    const int t = threadIdx.x;
    const int b = blockIdx.y;
    const int sl = blockIdx.x;
    unsigned C = cnt[b * 64];
    if (C > CANDCAP) C = CANDCAP;
    const uint64_t* cb = cand + ((size_t)b << 13);
    for (unsigned i = t; i < C; i += 256) lk[i] = cb[i];
    __syncthreads();

    const int base = b << 10;
    const float* xb = x + (size_t)b * NC * NA;
    for (int i0 = sl * 256 + t; i0 < (int)C; i0 += 1024) {
        uint64_t my = lk[i0];
        unsigned rank = 0;
        int j = 0;
        for (; j + 4 <= (int)C; j += 4) {
            rank += (lk[j] > my);
            rank += (lk[j + 1] > my);
            rank += (lk[j + 2] > my);
            rank += (lk[j + 3] > my);
        }
        for (; j < (int)C; ++j) rank += (lk[j] > my);
        if (rank < TOPK) {
            int idx = key_idx(my);
            tval[base + rank] = key_val(my);
            float x1 = xb[idx], y1 = xb[NA + idx], x2 = xb[2 * NA + idx], y2 = xb[3 * NA + idx];
            bx1[base + rank] = x1; by1[base + rank] = y1;
            bx2[base + rank] = x2; by2[base + rank] = y2;
            barr[base + rank] = (x2 - x1) * (y2 - y1);
            tcid[base + rank] = cid[b * NA + idx];
        }
    }
}

// ---- K4: suppression bit-matrix + last-block-fused serial sweep ------------
// grid (64, NB): block handles 16 rows. Last finishing block of each batch
// (device-scope done counter, fence/acquire) runs the greedy sweep + epilogue.
#define LDSPAD(j) ((j) + ((j) >> 6))
__global__ __launch_bounds__(256) void mask_sweep_kernel(const float* __restrict__ tval,
                                                         const int* __restrict__ tcid,
                                                         const float* __restrict__ bx1,
                                                         const float* __restrict__ by1,
                                                         const float* __restrict__ bx2,
                                                         const float* __restrict__ by2,
                                                         const float* __restrict__ barr,
                                                         uint64_t* __restrict__ M,
                                                         int* __restrict__ rowflag,
                                                         unsigned* __restrict__ done,
                                                         float* __restrict__ out) {
    __shared__ float sx1[TOPK + 16], sy1[TOPK + 16], sx2[TOPK + 16], sy2[TOPK + 16], sar[TOPK + 16];
    __shared__ int anyf[256];
    __shared__ int list[TOPK];
    __shared__ unsigned sdone;
    const int t = threadIdx.x;
    const int b = blockIdx.y;
    const int base = b << 10;

    for (int j = t; j < TOPK; j += 256) {
        int ji = LDSPAD(j);
        sx1[ji] = bx1[base + j]; sy1[ji] = by1[base + j];
        sx2[ji] = bx2[base + j]; sy2[ji] = by2[base + j];
        sar[ji] = barr[base + j];
    }
    __syncthreads();

    int w = t & 15;
    int r = (blockIdx.x << 4) + (t >> 4);
    int ri = LDSPAD(r);
    float ix1 = sx1[ri], iy1 = sy1[ri], ix2 = sx2[ri], iy2 = sy2[ri], ia = sar[ri];
    uint64_t m = 0;
#pragma unroll 8
    for (int jj = 0; jj < 64; ++jj) {
        int j = (w << 6) + jj;
        int ji = w * 65 + jj;
        float ltx = fmaxf(ix1, sx1[ji]);
        float lty = fmaxf(iy1, sy1[ji]);
        float rbx = fminf(ix2, sx2[ji]);
        float rby = fminf(iy2, sy2[ji]);
        float ww = fmaxf(rbx - ltx, 0.0f);
        float hh = fmaxf(rby - lty, 0.0f);
        float inter = ww * hh;
        float uni = ia + sar[ji] - inter;      // same op order as reference
        float iou = inter / fmaxf(uni, 1e-9f);
        if (j > r && iou > IOU_THR) m |= (1ULL << jj);
    }
    M[(((size_t)(base + r)) << 4) + w] = m;
    anyf[t] = (m != 0ULL);
    __syncthreads();
    if (w == 0) {
        int any = 0;
#pragma unroll
        for (int q = 0; q < 16; ++q) any |= anyf[t + q];
        bool valid = tval[base + r] > SCORE_THR;
        rowflag[base + r] = (any && valid) ? 1 : 0;
    }

    // ---- publish, then elect last block ----
    __syncthreads();
    __threadfence();
    if (t == 0)
        sdone = __hip_atomic_fetch_add(&done[b], 1u, __ATOMIC_ACQ_REL, __HIP_MEMORY_SCOPE_AGENT);
    __syncthreads();
    if (sdone != 63) return;

    // ---- serial greedy sweep (wave 0 only; no __syncthreads below) ----
    if (t >= 64) return;
    int l = t;
    int gg = l >> 4;
    w = l & 15;

    float tv[16];
#pragma unroll
    for (int s = 0; s < 16; ++s) tv[s] = tval[base + (s << 6) + l];

    uint64_t vword = 0;
#pragma unroll
    for (int s = 0; s < 16; ++s) {
        uint64_t bal = __ballot(tv[s] > SCORE_THR);
        if (l == s) vword = bal;
    }

    int cnt2 = 0;
#pragma unroll
    for (int s = 0; s < 16; ++s) {
        int flag = rowflag[base + (s << 6) + l];
        uint64_t mm = __ballot(flag != 0);
        if (flag) {
            int pos = cnt2 + __popcll(mm & ((1ULL << l) - 1ULL));
            list[pos] = (s << 6) + l;
        }
        cnt2 += __popcll(mm);
    }

    uint64_t remv = 0;
    for (int chunk = 0; chunk < cnt2; chunk += 64) {
        int mcnt = min(64, cnt2 - chunk);
        int idx_l = chunk + l;
        int myi = list[(idx_l < cnt2) ? idx_l : 0];
        uint64_t rows[16];
#pragma unroll
        for (int q = 0; q < 16; ++q) {
            int it = chunk + q * 4 + gg;
            int it2 = (it < cnt2) ? it : 0;
            uint64_t v = M[(((size_t)(base + list[it2])) << 4) + w];
            rows[q] = (it < cnt2) ? v : 0ULL;
        }
        for (int rr = 0; rr < mcnt; ++rr) {
            int i = __shfl(myi, rr, 64);
            uint64_t row = __shfl(rows[rr >> 2], ((rr & 3) << 4) + w, 64);
            uint64_t rb = __shfl(remv, i >> 6, 64);
            bool kept = !((rb >> (i & 63)) & 1ULL);
            remv |= (kept && l < 16) ? row : 0ULL;
        }
    }

    uint64_t kf = vword & ~remv;
#pragma unroll
    for (int s = 0; s < 16; ++s) {
        uint64_t kw = __shfl(kf, s, 64);
        bool kp = (kw >> l) & 1ULL;
        int k = (s << 6) + l;
        float x1 = bx1[base + k], y1 = by1[base + k];
        float x2 = bx2[base + k], y2 = by2[base + k];
        float* po = out + ((size_t)(base + k)) * 6;
        po[0] = kp ? x1 : 0.0f;
        po[1] = kp ? y1 : 0.0f;
        po[2] = kp ? x2 : 0.0f;
        po[3] = kp ? y2 : 0.0f;
        po[4] = kp ? tv[s] : 0.0f;
        po[5] = kp ? (float)tcid[base + k] : 0.0f;
        out[(size_t)NB * TOPK * 6 + base + k] = kp ? 1.0f : 0.0f;
    }
}

extern "C" void kernel_launch(void* const* d_in, const int* in_sizes, int n_in,
                              void* d_out, int out_size, void* d_ws, size_t ws_size,
                              hipStream_t stream) {
    const float* x = (const float*)d_in[0];
    float* out = (float*)d_out;
    char* ws = (char*)d_ws;

    size_t off = 0;
    auto alloc = [&](size_t bytes) { void* p = ws + off; off = (off + bytes + 255) & ~(size_t)255; return p; };
    float*    sval    = (float*)alloc((size_t)NB * NA * 4);
    int*      cid     = (int*)alloc((size_t)NB * NA * 4);
    // hist + cnt + done contiguous -> one memset
    unsigned* hist    = (unsigned*)alloc((size_t)NB * NBIN * 4);     // 512 KB
    unsigned* cnt     = (unsigned*)alloc((size_t)NB * 64 * 4);       // 4 KB (256B stride/batch)
    unsigned* done    = (unsigned*)alloc(256);                       // 16 used
    uint64_t* cand    = (uint64_t*)alloc((size_t)NB * CANDCAP * 8);
    float*    tval    = (float*)alloc((size_t)NB * TOPK * 4);
    float*    bx1     = (float*)alloc((size_t)NB * TOPK * 4);
    float*    by1     = (float*)alloc((size_t)NB * TOPK * 4);
    float*    bx2     = (float*)alloc((size_t)NB * TOPK * 4);
    float*    by2     = (float*)alloc((size_t)NB * TOPK * 4);
    float*    barr    = (float*)alloc((size_t)NB * TOPK * 4);
    int*      tcid    = (int*)alloc((size_t)NB * TOPK * 4);
    int*      rowflag = (int*)alloc((size_t)NB * TOPK * 4);
    uint64_t* M       = (uint64_t*)alloc((size_t)NB * TOPK * 16 * 8);

    size_t zbytes = (size_t)NB * NBIN * 4 + (size_t)NB * 64 * 4 + 256;
    hipMemsetAsync(hist, 0, zbytes, stream);

    score_hist_kernel<<<dim3(33, NB), 256, 0, stream>>>(x, sval, cid, hist);
    select_kernel<<<dim3(16, NB), 256, 0, stream>>>(sval, hist, cand, cnt);
    rank_gather_kernel<<<dim3(4, NB), 256, 0, stream>>>(x, cid, cand, cnt, tval,
                                                        bx1, by1, bx2, by2, barr, tcid);
    mask_sweep_kernel<<<dim3(64, NB), 256, 0, stream>>>(tval, tcid, bx1, by1, bx2, by2,
                                                        barr, M, rowflag, done, out);
}